// Round 1
// baseline (6352.829 us; speedup 1.0000x reference)
//
#include <hip/hip_runtime.h>

#define N_NODES 50000
#define N_EDGES 500000
#define DIM_A 128
#define DIM_V 32
#define CHAN 32
#define EPB 32

// ---------------- node projection kernel ----------------
// L0[n][c] = sum_d x_a[n][d] * W_L0[c][d]            (N x 32)
// L1[n][c*3+i] = sum_d x_v[n][d][i] * W_L1[c][d]     (N x 96)
__global__ __launch_bounds__(256) void node_proj_kernel(
    const float* __restrict__ x_a, const float* __restrict__ x_v,
    const float* __restrict__ W_L0, const float* __restrict__ W_L1,
    float* __restrict__ L0, float* __restrict__ L1)
{
    int t = threadIdx.x;
    int n = blockIdx.x * 8 + (t >> 5);
    int c = t & 31;
    if (n >= N_NODES) return;

    const float4* xa = (const float4*)(x_a + (size_t)n * DIM_A);
    const float4* w0 = (const float4*)(W_L0 + c * DIM_A);
    float acc = 0.f;
#pragma unroll 8
    for (int k = 0; k < DIM_A / 4; ++k) {
        float4 x = xa[k]; float4 w = w0[k];
        acc += x.x * w.x + x.y * w.y + x.z * w.z + x.w * w.w;
    }
    L0[(size_t)n * 32 + c] = acc;

    const float* xv = x_v + (size_t)n * DIM_V * 3;
    const float* w1 = W_L1 + c * DIM_V;
    float a0 = 0.f, a1 = 0.f, a2 = 0.f;
#pragma unroll 8
    for (int d = 0; d < DIM_V; ++d) {
        float w = w1[d];
        a0 += xv[d * 3 + 0] * w;
        a1 += xv[d * 3 + 1] * w;
        a2 += xv[d * 3 + 2] * w;
    }
    float* o = L1 + (size_t)n * 96 + c * 3;
    o[0] = a0; o[1] = a1; o[2] = a2;
}

// ---------------- edge kernel ----------------
// LDS layout (floats). Padded strides chosen so lanes (varying in e) hit
// distinct banks: 36 (=4 mod 32, x4-aligned), 99 (odd*3... 99%32=3, gcd(3,32)=1),
// 132 (132%32=4, /4=33 odd -> distinct 4-bank groups for b128).
#define O_A0   0                  // [32][36]  y000 = l_a * rad_enc
#define O_Y110 1152               // [32][36]  y110 = rad_enc * (l_v . r_s)
#define O_RS   2304               // [32][4]   r_s
#define O_U    2432
#define O_A1   (O_U)              // [32][99]  rad_enc * l_v        (phase 2)
#define O_A2   (O_U + 3168)       // [32][99]  rad_enc * (l_v x r_s)(phase 2)
#define O_PSI0 (O_U)              // [32][132] psi_a pre-MLP        (phase 3+)
#define O_H1   (O_U + 4224)       // [32][132]
#define O_H2   (O_U + 8448)       // [32][132]
#define SMEM_FLOATS (O_U + 12672) // 15104 floats = 60416 B -> 2 blocks/CU

__device__ __forceinline__ float leaky(float x) {
    return x >= 0.f ? x : 0.1f * x;
}

__global__ __launch_bounds__(256, 2) void edge_kernel(
    const float* __restrict__ r_ij, const int* __restrict__ src, const int* __restrict__ dst,
    const float* __restrict__ L0, const float* __restrict__ L1,
    const float* __restrict__ W_enc, const float* __restrict__ b_enc,
    const float* __restrict__ Wy000, const float* __restrict__ Wy110,
    const float* __restrict__ Wy011, const float* __restrict__ Wy101,
    const float* __restrict__ Wy111,
    const float* __restrict__ Wm1, const float* __restrict__ bm1,
    const float* __restrict__ Wm2, const float* __restrict__ bm2,
    const float* __restrict__ Wm3,
    float* __restrict__ B_a, float* __restrict__ B_v)
{
    __shared__ float sm[SMEM_FLOATS];
    const int t = threadIdx.x;
    const int e0 = blockIdx.x * EPB;   // E = 500000 = 15625 * 32, exact

    // ---- phase 1: per-edge embeddings -> LDS ----
    {
        int e = t >> 3;        // 0..31
        int part = t & 7;      // 0..7 -> 4 channels each
        int ge = e0 + e;
        float rx = r_ij[ge * 3 + 0];
        float ry = r_ij[ge * 3 + 1];
        float rz = r_ij[ge * 3 + 2];
        float r = sqrtf(rx * rx + ry * ry + rz * rz);

        // gaussian RBF: centers k*(5/7), width 5/8
        float rad[8];
#pragma unroll
        for (int k = 0; k < 8; ++k) {
            float d = (r - (5.0f / 7.0f) * (float)k) * 1.6f; // 1/0.625
            rad[k] = expf(-d * d);
        }
        // tens_sigmoid on 1.4*r_ij
        float n14 = 1.4f * r;
        float tt = tanhf(n14) / fmaxf(n14, 1e-6f);
        float rsx = 1.4f * rx * tt, rsy = 1.4f * ry * tt, rsz = 1.4f * rz * tt;
        if (part == 0) {
            sm[O_RS + e * 4 + 0] = rsx;
            sm[O_RS + e * 4 + 1] = rsy;
            sm[O_RS + e * 4 + 2] = rsz;
        }

        int dn = dst[ge];
        float4 la4 = *(const float4*)(L0 + (size_t)dn * 32 + part * 4);
        float laa[4] = { la4.x, la4.y, la4.z, la4.w };
        const float* lvp = L1 + (size_t)dn * 96 + part * 12;

#pragma unroll
        for (int j = 0; j < 4; ++j) {
            int c = part * 4 + j;
            float re = b_enc[c];
#pragma unroll
            for (int k = 0; k < 8; ++k) re += rad[k] * W_enc[c * 8 + k];
            float lvx = lvp[j * 3 + 0], lvy = lvp[j * 3 + 1], lvz = lvp[j * 3 + 2];
            sm[O_A0 + e * 36 + c]   = laa[j] * re;
            sm[O_Y110 + e * 36 + c] = re * (lvx * rsx + lvy * rsy + lvz * rsz);
            sm[O_A1 + e * 99 + c * 3 + 0] = re * lvx;
            sm[O_A1 + e * 99 + c * 3 + 1] = re * lvy;
            sm[O_A1 + e * 99 + c * 3 + 2] = re * lvz;
            sm[O_A2 + e * 99 + c * 3 + 0] = re * (lvy * rsz - lvz * rsy);
            sm[O_A2 + e * 99 + c * 3 + 1] = re * (lvz * rsx - lvx * rsz);
            sm[O_A2 + e * 99 + c * 3 + 2] = re * (lvx * rsy - lvy * rsx);
        }
    }
    __syncthreads();

    // ---- phase 2: psi_v (rank-1) + atomic scatter to B_v ----
    {
        int e = t & 31;
        int dg = t >> 5;      // 0..7, 4 d's each
        int ge = e0 + e;
        int sn = src[ge];
        float rsx = sm[O_RS + e * 4 + 0];
        float rsy = sm[O_RS + e * 4 + 1];
        float rsz = sm[O_RS + e * 4 + 2];
        float s0[4] = {0, 0, 0, 0};
        float ax[4] = {0, 0, 0, 0}, ay[4] = {0, 0, 0, 0}, az[4] = {0, 0, 0, 0};
        for (int c = 0; c < 32; ++c) {
            float a0  = sm[O_A0 + e * 36 + c];
            float a1x = sm[O_A1 + e * 99 + c * 3 + 0];
            float a1y = sm[O_A1 + e * 99 + c * 3 + 1];
            float a1z = sm[O_A1 + e * 99 + c * 3 + 2];
            float a2x = sm[O_A2 + e * 99 + c * 3 + 0];
            float a2y = sm[O_A2 + e * 99 + c * 3 + 1];
            float a2z = sm[O_A2 + e * 99 + c * 3 + 2];
#pragma unroll
            for (int dd = 0; dd < 4; ++dd) {
                int d = dg * 4 + dd;
                float w011 = Wy011[d * 32 + c];
                float w101 = Wy101[d * 32 + c];
                float w111 = Wy111[d * 32 + c];
                s0[dd] += w011 * a0;
                ax[dd] += w101 * a1x + w111 * a2x;
                ay[dd] += w101 * a1y + w111 * a2y;
                az[dd] += w101 * a1z + w111 * a2z;
            }
        }
        float* outp = B_v + (size_t)sn * 96;
#pragma unroll
        for (int dd = 0; dd < 4; ++dd) {
            int d = dg * 4 + dd;
            atomicAdd(&outp[d * 3 + 0], 0.1f * (s0[dd] * rsx + ax[dd]));
            atomicAdd(&outp[d * 3 + 1], 0.1f * (s0[dd] * rsy + ay[dd]));
            atomicAdd(&outp[d * 3 + 2], 0.1f * (s0[dd] * rsz + az[dd]));
        }
    }
    __syncthreads();  // A1/A2 reads done before PSI0 overwrites that region

    // ---- phase 3: psi_a pre-MLP = y000@Wy000^T + y110@Wy110^T -> LDS ----
    const int e3 = t & 31;
    const int og = t >> 5;    // 0..7, 16 outputs each
    {
        float accp[16];
#pragma unroll
        for (int j = 0; j < 16; ++j) accp[j] = 0.f;
        const float4* A0v = (const float4*)(sm + O_A0 + e3 * 36);
        const float4* Y1v = (const float4*)(sm + O_Y110 + e3 * 36);
        for (int c4 = 0; c4 < 8; ++c4) {
            float4 y0 = A0v[c4];
            float4 y1 = Y1v[c4];
#pragma unroll
            for (int j = 0; j < 16; ++j) {
                int o = og * 16 + j;
                float4 w0 = *(const float4*)(Wy000 + o * 32 + c4 * 4);
                float4 w1 = *(const float4*)(Wy110 + o * 32 + c4 * 4);
                accp[j] += y0.x * w0.x + y0.y * w0.y + y0.z * w0.z + y0.w * w0.w
                         + y1.x * w1.x + y1.y * w1.y + y1.z * w1.z + y1.w * w1.w;
            }
        }
        float4* P = (float4*)(sm + O_PSI0 + e3 * 132 + og * 16);
#pragma unroll
        for (int q = 0; q < 4; ++q)
            P[q] = make_float4(accp[4 * q], accp[4 * q + 1], accp[4 * q + 2], accp[4 * q + 3]);
    }
    __syncthreads();

    // ---- phase 4a: h1 = leaky(psi0 @ Wm1^T + bm1) ----
    {
        float h[16];
#pragma unroll
        for (int j = 0; j < 16; ++j) h[j] = bm1[og * 16 + j];
        const float4* P = (const float4*)(sm + O_PSI0 + e3 * 132);
        for (int k4 = 0; k4 < 32; ++k4) {
            float4 p = P[k4];
#pragma unroll
            for (int j = 0; j < 16; ++j) {
                const float4 w = *(const float4*)(Wm1 + (og * 16 + j) * 128 + k4 * 4);
                h[j] += p.x * w.x + p.y * w.y + p.z * w.z + p.w * w.w;
            }
        }
        float4* H = (float4*)(sm + O_H1 + e3 * 132 + og * 16);
#pragma unroll
        for (int q = 0; q < 4; ++q)
            H[q] = make_float4(leaky(h[4 * q]), leaky(h[4 * q + 1]),
                               leaky(h[4 * q + 2]), leaky(h[4 * q + 3]));
    }
    __syncthreads();

    // ---- phase 4b: h2 = leaky(h1 @ Wm2^T + bm2) ----
    {
        float h[16];
#pragma unroll
        for (int j = 0; j < 16; ++j) h[j] = bm2[og * 16 + j];
        const float4* P = (const float4*)(sm + O_H1 + e3 * 132);
        for (int k4 = 0; k4 < 32; ++k4) {
            float4 p = P[k4];
#pragma unroll
            for (int j = 0; j < 16; ++j) {
                const float4 w = *(const float4*)(Wm2 + (og * 16 + j) * 128 + k4 * 4);
                h[j] += p.x * w.x + p.y * w.y + p.z * w.z + p.w * w.w;
            }
        }
        float4* H = (float4*)(sm + O_H2 + e3 * 132 + og * 16);
#pragma unroll
        for (int q = 0; q < 4; ++q)
            H[q] = make_float4(leaky(h[4 * q]), leaky(h[4 * q + 1]),
                               leaky(h[4 * q + 2]), leaky(h[4 * q + 3]));
    }
    __syncthreads();

    // ---- phase 4c: psi_a = psi0 + h2 @ Wm3^T ; atomic scatter to B_a ----
    {
        float f[16];
#pragma unroll
        for (int j = 0; j < 16; ++j) f[j] = 0.f;
        const float4* P = (const float4*)(sm + O_H2 + e3 * 132);
        for (int k4 = 0; k4 < 32; ++k4) {
            float4 p = P[k4];
#pragma unroll
            for (int j = 0; j < 16; ++j) {
                const float4 w = *(const float4*)(Wm3 + (og * 16 + j) * 128 + k4 * 4);
                f[j] += p.x * w.x + p.y * w.y + p.z * w.z + p.w * w.w;
            }
        }
        int sn = src[e0 + e3];
        float* outp = B_a + (size_t)sn * 128 + og * 16;
        const float* P0 = sm + O_PSI0 + e3 * 132 + og * 16;
#pragma unroll
        for (int j = 0; j < 16; ++j)
            atomicAdd(&outp[j], 0.1f * (f[j] + P0[j]));
    }
}

extern "C" void kernel_launch(void* const* d_in, const int* in_sizes, int n_in,
                              void* d_out, int out_size, void* d_ws, size_t ws_size,
                              hipStream_t stream) {
    const float* x_a   = (const float*)d_in[0];
    const float* x_v   = (const float*)d_in[1];
    const float* r_ij  = (const float*)d_in[2];
    const int*   src   = (const int*)d_in[3];
    const int*   dst   = (const int*)d_in[4];
    const float* W_L0  = (const float*)d_in[5];
    const float* W_L1  = (const float*)d_in[6];
    const float* W_enc = (const float*)d_in[7];
    const float* b_enc = (const float*)d_in[8];
    const float* Wy000 = (const float*)d_in[9];
    const float* Wy110 = (const float*)d_in[10];
    const float* Wy011 = (const float*)d_in[11];
    const float* Wy101 = (const float*)d_in[12];
    const float* Wy111 = (const float*)d_in[13];
    const float* Wm1   = (const float*)d_in[14];
    const float* bm1   = (const float*)d_in[15];
    const float* Wm2   = (const float*)d_in[16];
    const float* bm2   = (const float*)d_in[17];
    const float* Wm3   = (const float*)d_in[18];

    float* out = (float*)d_out;
    float* B_a = out;                                  // N x 128
    float* B_v = out + (size_t)N_NODES * DIM_A;        // N x 32 x 3

    float* L0 = (float*)d_ws;                          // N x 32
    float* L1 = L0 + (size_t)N_NODES * 32;             // N x 96

    // zero outputs (atomically accumulated)
    hipMemsetAsync(d_out, 0, (size_t)out_size * sizeof(float), stream);

    node_proj_kernel<<<(N_NODES + 7) / 8, 256, 0, stream>>>(x_a, x_v, W_L0, W_L1, L0, L1);

    edge_kernel<<<N_EDGES / EPB, 256, 0, stream>>>(
        r_ij, src, dst, L0, L1, W_enc, b_enc,
        Wy000, Wy110, Wy011, Wy101, Wy111,
        Wm1, bm1, Wm2, bm2, Wm3, B_a, B_v);
}

// Round 2
// 4859.891 us; speedup vs baseline: 1.3072x; 1.3072x over previous
//
#include <hip/hip_runtime.h>

#define N_NODES 50000
#define N_EDGES 500000
#define DIM_A 128
#define DIM_V 32
#define CHAN 32
#define NPB 16      // nodes per block in main kernel (50000/16 = 3125 blocks)
#define TILE 32     // edges processed per tile iteration

// ---------------- node projection kernel ----------------
__global__ __launch_bounds__(256) void node_proj_kernel(
    const float* __restrict__ x_a, const float* __restrict__ x_v,
    const float* __restrict__ W_L0, const float* __restrict__ W_L1,
    float* __restrict__ L0, float* __restrict__ L1)
{
    int t = threadIdx.x;
    int n = blockIdx.x * 8 + (t >> 5);
    int c = t & 31;
    if (n >= N_NODES) return;

    const float4* xa = (const float4*)(x_a + (size_t)n * DIM_A);
    const float4* w0 = (const float4*)(W_L0 + c * DIM_A);
    float acc = 0.f;
#pragma unroll 8
    for (int k = 0; k < DIM_A / 4; ++k) {
        float4 x = xa[k]; float4 w = w0[k];
        acc += x.x * w.x + x.y * w.y + x.z * w.z + x.w * w.w;
    }
    L0[(size_t)n * 32 + c] = acc;

    const float* xv = x_v + (size_t)n * DIM_V * 3;
    const float* w1 = W_L1 + c * DIM_V;
    float a0 = 0.f, a1 = 0.f, a2 = 0.f;
#pragma unroll 8
    for (int d = 0; d < DIM_V; ++d) {
        float w = w1[d];
        a0 += xv[d * 3 + 0] * w;
        a1 += xv[d * 3 + 1] * w;
        a2 += xv[d * 3 + 2] * w;
    }
    float* o = L1 + (size_t)n * 96 + c * 3;
    o[0] = a0; o[1] = a1; o[2] = a2;
}

// ---------------- counting-sort kernels (edges sorted by src) ----------------
__global__ __launch_bounds__(256) void hist_kernel(const int* __restrict__ src,
                                                   int* __restrict__ deg)
{
    int i = blockIdx.x * 256 + threadIdx.x;
    if (i < N_EDGES) atomicAdd(&deg[src[i]], 1);
}

__global__ __launch_bounds__(1024) void scan_kernel(const int* __restrict__ deg,
                                                    int* __restrict__ offs,
                                                    int* __restrict__ cursor)
{
    __shared__ int buf[1024];
    __shared__ int s_carry;
    int t = threadIdx.x;
    if (t == 0) s_carry = 0;
    __syncthreads();
    for (int base = 0; base < N_NODES; base += 1024) {
        int v = (base + t < N_NODES) ? deg[base + t] : 0;
        buf[t] = v;
        __syncthreads();
        for (int off = 1; off < 1024; off <<= 1) {
            int x = (t >= off) ? buf[t - off] : 0;
            __syncthreads();
            buf[t] += x;
            __syncthreads();
        }
        int incl = buf[t];
        int carry = s_carry;
        if (base + t < N_NODES) {
            int excl = carry + incl - v;
            offs[base + t] = excl;
            cursor[base + t] = excl;
        }
        __syncthreads();
        if (t == 1023) s_carry = carry + incl;
        __syncthreads();
    }
    if (t == 0) offs[N_NODES] = s_carry;
}

__global__ __launch_bounds__(256) void scatter_kernel(const int* __restrict__ src,
                                                      int* __restrict__ cursor,
                                                      int* __restrict__ eids)
{
    int i = blockIdx.x * 256 + threadIdx.x;
    if (i < N_EDGES) {
        int p = atomicAdd(&cursor[src[i]], 1);
        eids[p] = i;
    }
}

// ---------------- main edge kernel (per-node-owner, no global atomics) ------
// LDS work-region layout (floats), padded strides to avoid bank conflicts.
#define O_A0   0                  // [32][36]  y000 = l_a * rad_enc
#define O_Y110 1152               // [32][36]  y110 = rad_enc * (l_v . r_s)
#define O_RS   2304               // [32][4]   r_s
#define O_U    2432
#define O_A1   (O_U)              // [32][99]  rad_enc * l_v        (phase 2)
#define O_A2   (O_U + 3168)       // [32][99]  rad_enc * (l_v x r_s)(phase 2)
#define O_PSI0 (O_U)              // [32][132] psi_a pre-MLP        (phase 3+)
#define O_H1   (O_U + 4224)       // [32][132]
#define O_H2   (O_U + 8448)       // [32][132]
#define O_WORK_END (O_U + 12672)  // 15104 floats
#define O_ACCA O_WORK_END               // [NPB][132] node accum for B_a
#define O_ACCV (O_ACCA + NPB * 132)     // [NPB][100] node accum for B_v
#define SMEM_FLOATS (O_ACCV + NPB * 100) // 18816 floats = 75264 B -> 2 blocks/CU

__device__ __forceinline__ float leaky(float x) {
    return x >= 0.f ? x : 0.1f * x;
}

__global__ __launch_bounds__(256, 2) void main_kernel(
    const float* __restrict__ r_ij, const int* __restrict__ src, const int* __restrict__ dst,
    const int* __restrict__ offs, const int* __restrict__ eids,
    const float* __restrict__ L0, const float* __restrict__ L1,
    const float* __restrict__ W_enc, const float* __restrict__ b_enc,
    const float* __restrict__ Wy000, const float* __restrict__ Wy110,
    const float* __restrict__ Wy011, const float* __restrict__ Wy101,
    const float* __restrict__ Wy111,
    const float* __restrict__ Wm1, const float* __restrict__ bm1,
    const float* __restrict__ Wm2, const float* __restrict__ bm2,
    const float* __restrict__ Wm3,
    float* __restrict__ B_a, float* __restrict__ B_v)
{
    __shared__ float sm[SMEM_FLOATS];
    __shared__ int s_li[TILE];      // local node index of each tile edge
    const int t = threadIdx.x;
    const int nb0 = blockIdx.x * NPB;

    // zero node accumulators
    for (int i = t; i < NPB * 132; i += 256) sm[O_ACCA + i] = 0.f;
    for (int i = t; i < NPB * 100; i += 256) sm[O_ACCV + i] = 0.f;

    const int estart = offs[nb0];
    const int eend   = offs[nb0 + NPB];
    __syncthreads();

    for (int eb = estart; eb < eend; eb += TILE) {
        const int ne = min(TILE, eend - eb);

        // ---- phase 1: per-edge embeddings -> LDS ----
        {
            int e = t >> 3;        // 0..31
            int part = t & 7;      // 0..7 -> 4 channels each
            if (e < ne) {
                int ge = eids[eb + e];
                float rx = r_ij[ge * 3 + 0];
                float ry = r_ij[ge * 3 + 1];
                float rz = r_ij[ge * 3 + 2];
                float r = sqrtf(rx * rx + ry * ry + rz * rz);

                float rad[8];
#pragma unroll
                for (int k = 0; k < 8; ++k) {
                    float d = (r - (5.0f / 7.0f) * (float)k) * 1.6f;
                    rad[k] = expf(-d * d);
                }
                float n14 = 1.4f * r;
                float tt = tanhf(n14) / fmaxf(n14, 1e-6f);
                float rsx = 1.4f * rx * tt, rsy = 1.4f * ry * tt, rsz = 1.4f * rz * tt;
                if (part == 0) {
                    sm[O_RS + e * 4 + 0] = rsx;
                    sm[O_RS + e * 4 + 1] = rsy;
                    sm[O_RS + e * 4 + 2] = rsz;
                    s_li[e] = src[ge] - nb0;
                }

                int dn = dst[ge];
                float4 la4 = *(const float4*)(L0 + (size_t)dn * 32 + part * 4);
                float laa[4] = { la4.x, la4.y, la4.z, la4.w };
                const float* lvp = L1 + (size_t)dn * 96 + part * 12;

#pragma unroll
                for (int j = 0; j < 4; ++j) {
                    int c = part * 4 + j;
                    float re = b_enc[c];
#pragma unroll
                    for (int k = 0; k < 8; ++k) re += rad[k] * W_enc[c * 8 + k];
                    float lvx = lvp[j * 3 + 0], lvy = lvp[j * 3 + 1], lvz = lvp[j * 3 + 2];
                    sm[O_A0 + e * 36 + c]   = laa[j] * re;
                    sm[O_Y110 + e * 36 + c] = re * (lvx * rsx + lvy * rsy + lvz * rsz);
                    sm[O_A1 + e * 99 + c * 3 + 0] = re * lvx;
                    sm[O_A1 + e * 99 + c * 3 + 1] = re * lvy;
                    sm[O_A1 + e * 99 + c * 3 + 2] = re * lvz;
                    sm[O_A2 + e * 99 + c * 3 + 0] = re * (lvy * rsz - lvz * rsy);
                    sm[O_A2 + e * 99 + c * 3 + 1] = re * (lvz * rsx - lvx * rsz);
                    sm[O_A2 + e * 99 + c * 3 + 2] = re * (lvx * rsy - lvy * rsx);
                }
            }
        }
        __syncthreads();

        // ---- phase 2: psi_v (rank-1) -> LDS accumulator ----
        {
            int e = t & 31;
            int dg = t >> 5;      // 0..7, 4 d's each
            float rsx = sm[O_RS + e * 4 + 0];
            float rsy = sm[O_RS + e * 4 + 1];
            float rsz = sm[O_RS + e * 4 + 2];
            float s0[4] = {0, 0, 0, 0};
            float ax[4] = {0, 0, 0, 0}, ay[4] = {0, 0, 0, 0}, az[4] = {0, 0, 0, 0};
            for (int c = 0; c < 32; ++c) {
                float a0  = sm[O_A0 + e * 36 + c];
                float a1x = sm[O_A1 + e * 99 + c * 3 + 0];
                float a1y = sm[O_A1 + e * 99 + c * 3 + 1];
                float a1z = sm[O_A1 + e * 99 + c * 3 + 2];
                float a2x = sm[O_A2 + e * 99 + c * 3 + 0];
                float a2y = sm[O_A2 + e * 99 + c * 3 + 1];
                float a2z = sm[O_A2 + e * 99 + c * 3 + 2];
#pragma unroll
                for (int dd = 0; dd < 4; ++dd) {
                    int d = dg * 4 + dd;
                    float w011 = Wy011[d * 32 + c];
                    float w101 = Wy101[d * 32 + c];
                    float w111 = Wy111[d * 32 + c];
                    s0[dd] += w011 * a0;
                    ax[dd] += w101 * a1x + w111 * a2x;
                    ay[dd] += w101 * a1y + w111 * a2y;
                    az[dd] += w101 * a1z + w111 * a2z;
                }
            }
            if (e < ne) {
                float* acc = sm + O_ACCV + s_li[e] * 100;
#pragma unroll
                for (int dd = 0; dd < 4; ++dd) {
                    int d = dg * 4 + dd;
                    atomicAdd(&acc[d * 3 + 0], s0[dd] * rsx + ax[dd]);
                    atomicAdd(&acc[d * 3 + 1], s0[dd] * rsy + ay[dd]);
                    atomicAdd(&acc[d * 3 + 2], s0[dd] * rsz + az[dd]);
                }
            }
        }
        __syncthreads();  // A1/A2 reads done before PSI0 overwrites that region

        // ---- phase 3: psi_a pre-MLP = y000@Wy000^T + y110@Wy110^T -> LDS ----
        const int e3 = t & 31;
        const int og = t >> 5;    // 0..7, 16 outputs each
        {
            float accp[16];
#pragma unroll
            for (int j = 0; j < 16; ++j) accp[j] = 0.f;
            const float4* A0v = (const float4*)(sm + O_A0 + e3 * 36);
            const float4* Y1v = (const float4*)(sm + O_Y110 + e3 * 36);
            for (int c4 = 0; c4 < 8; ++c4) {
                float4 y0 = A0v[c4];
                float4 y1 = Y1v[c4];
#pragma unroll
                for (int j = 0; j < 16; ++j) {
                    int o = og * 16 + j;
                    float4 w0 = *(const float4*)(Wy000 + o * 32 + c4 * 4);
                    float4 w1 = *(const float4*)(Wy110 + o * 32 + c4 * 4);
                    accp[j] += y0.x * w0.x + y0.y * w0.y + y0.z * w0.z + y0.w * w0.w
                             + y1.x * w1.x + y1.y * w1.y + y1.z * w1.z + y1.w * w1.w;
                }
            }
            float4* P = (float4*)(sm + O_PSI0 + e3 * 132 + og * 16);
#pragma unroll
            for (int q = 0; q < 4; ++q)
                P[q] = make_float4(accp[4 * q], accp[4 * q + 1], accp[4 * q + 2], accp[4 * q + 3]);
        }
        __syncthreads();

        // ---- phase 4a: h1 = leaky(psi0 @ Wm1^T + bm1) ----
        {
            float h[16];
#pragma unroll
            for (int j = 0; j < 16; ++j) h[j] = bm1[og * 16 + j];
            const float4* P = (const float4*)(sm + O_PSI0 + e3 * 132);
            for (int k4 = 0; k4 < 32; ++k4) {
                float4 p = P[k4];
#pragma unroll
                for (int j = 0; j < 16; ++j) {
                    const float4 w = *(const float4*)(Wm1 + (og * 16 + j) * 128 + k4 * 4);
                    h[j] += p.x * w.x + p.y * w.y + p.z * w.z + p.w * w.w;
                }
            }
            float4* H = (float4*)(sm + O_H1 + e3 * 132 + og * 16);
#pragma unroll
            for (int q = 0; q < 4; ++q)
                H[q] = make_float4(leaky(h[4 * q]), leaky(h[4 * q + 1]),
                                   leaky(h[4 * q + 2]), leaky(h[4 * q + 3]));
        }
        __syncthreads();

        // ---- phase 4b: h2 = leaky(h1 @ Wm2^T + bm2) ----
        {
            float h[16];
#pragma unroll
            for (int j = 0; j < 16; ++j) h[j] = bm2[og * 16 + j];
            const float4* P = (const float4*)(sm + O_H1 + e3 * 132);
            for (int k4 = 0; k4 < 32; ++k4) {
                float4 p = P[k4];
#pragma unroll
                for (int j = 0; j < 16; ++j) {
                    const float4 w = *(const float4*)(Wm2 + (og * 16 + j) * 128 + k4 * 4);
                    h[j] += p.x * w.x + p.y * w.y + p.z * w.z + p.w * w.w;
                }
            }
            float4* H = (float4*)(sm + O_H2 + e3 * 132 + og * 16);
#pragma unroll
            for (int q = 0; q < 4; ++q)
                H[q] = make_float4(leaky(h[4 * q]), leaky(h[4 * q + 1]),
                                   leaky(h[4 * q + 2]), leaky(h[4 * q + 3]));
        }
        __syncthreads();

        // ---- phase 4c: psi_a = psi0 + h2 @ Wm3^T -> LDS accumulator ----
        {
            float f[16];
#pragma unroll
            for (int j = 0; j < 16; ++j) f[j] = 0.f;
            const float4* P = (const float4*)(sm + O_H2 + e3 * 132);
            for (int k4 = 0; k4 < 32; ++k4) {
                float4 p = P[k4];
#pragma unroll
                for (int j = 0; j < 16; ++j) {
                    const float4 w = *(const float4*)(Wm3 + (og * 16 + j) * 128 + k4 * 4);
                    f[j] += p.x * w.x + p.y * w.y + p.z * w.z + p.w * w.w;
                }
            }
            if (e3 < ne) {
                float* acc = sm + O_ACCA + s_li[e3] * 132 + og * 16;
                const float* P0 = sm + O_PSI0 + e3 * 132 + og * 16;
#pragma unroll
                for (int j = 0; j < 16; ++j)
                    atomicAdd(&acc[j], f[j] + P0[j]);
            }
        }
        __syncthreads();  // acc/PSI0 reads done before next tile's phase 1/3 writes
    }

    // ---- final: plain coalesced stores (each node owned by exactly one block)
    for (int i = t; i < NPB * DIM_A; i += 256) {
        int node = i >> 7, col = i & 127;
        B_a[(size_t)(nb0 + node) * DIM_A + col] = 0.1f * sm[O_ACCA + node * 132 + col];
    }
    for (int i = t; i < NPB * 96; i += 256) {
        int node = i / 96, col = i % 96;
        B_v[(size_t)(nb0 + node) * 96 + col] = 0.1f * sm[O_ACCV + node * 100 + col];
    }
}

extern "C" void kernel_launch(void* const* d_in, const int* in_sizes, int n_in,
                              void* d_out, int out_size, void* d_ws, size_t ws_size,
                              hipStream_t stream) {
    const float* x_a   = (const float*)d_in[0];
    const float* x_v   = (const float*)d_in[1];
    const float* r_ij  = (const float*)d_in[2];
    const int*   src   = (const int*)d_in[3];
    const int*   dst   = (const int*)d_in[4];
    const float* W_L0  = (const float*)d_in[5];
    const float* W_L1  = (const float*)d_in[6];
    const float* W_enc = (const float*)d_in[7];
    const float* b_enc = (const float*)d_in[8];
    const float* Wy000 = (const float*)d_in[9];
    const float* Wy110 = (const float*)d_in[10];
    const float* Wy011 = (const float*)d_in[11];
    const float* Wy101 = (const float*)d_in[12];
    const float* Wy111 = (const float*)d_in[13];
    const float* Wm1   = (const float*)d_in[14];
    const float* bm1   = (const float*)d_in[15];
    const float* Wm2   = (const float*)d_in[16];
    const float* bm2   = (const float*)d_in[17];
    const float* Wm3   = (const float*)d_in[18];

    float* out = (float*)d_out;
    float* B_a = out;                                  // N x 128
    float* B_v = out + (size_t)N_NODES * DIM_A;        // N x 32 x 3

    // workspace layout
    float* L0     = (float*)d_ws;                      // N x 32
    float* L1     = L0 + (size_t)N_NODES * 32;         // N x 96
    int*   deg    = (int*)(L1 + (size_t)N_NODES * 96); // N
    int*   offs   = deg + N_NODES;                     // N + 1
    int*   cursor = offs + N_NODES + 1;                // N
    int*   eids   = cursor + N_NODES;                  // E

    hipMemsetAsync(deg, 0, N_NODES * sizeof(int), stream);

    node_proj_kernel<<<(N_NODES + 7) / 8, 256, 0, stream>>>(x_a, x_v, W_L0, W_L1, L0, L1);

    hist_kernel<<<(N_EDGES + 255) / 256, 256, 0, stream>>>(src, deg);
    scan_kernel<<<1, 1024, 0, stream>>>(deg, offs, cursor);
    scatter_kernel<<<(N_EDGES + 255) / 256, 256, 0, stream>>>(src, cursor, eids);

    main_kernel<<<N_NODES / NPB, 256, 0, stream>>>(
        r_ij, src, dst, offs, eids, L0, L1, W_enc, b_enc,
        Wy000, Wy110, Wy011, Wy101, Wy111,
        Wm1, bm1, Wm2, bm2, Wm3, B_a, B_v);
}

// Round 3
// 1002.861 us; speedup vs baseline: 6.3347x; 4.8460x over previous
//
#include <hip/hip_runtime.h>
#include <hip/hip_bf16.h>

#define N_NODES 50000
#define N_EDGES 500000
#define DIM_A 128
#define DIM_V 32
#define CHAN 32
#define EB 64   // edges per block in edge_mfma_kernel

typedef __attribute__((ext_vector_type(8))) short short8;
typedef __attribute__((ext_vector_type(8))) unsigned short ushort8;
typedef __attribute__((ext_vector_type(4))) float f32x4;
typedef unsigned short ushort;

__device__ __forceinline__ ushort f2bf(float x) {
    __hip_bfloat16 h = __float2bfloat16(x);
    return *reinterpret_cast<ushort*>(&h);
}
__device__ __forceinline__ float bf2f(ushort u) {
    union { float f; unsigned int i; } v; v.i = ((unsigned int)u) << 16; return v.f;
}
__device__ __forceinline__ float leaky(float x) {
    return x >= 0.f ? x : 0.1f * x;
}

// ---------------- weight conversion (fp32 -> bf16, concatenated) ------------
__global__ __launch_bounds__(256) void convw_kernel(
    const float* __restrict__ Wy000, const float* __restrict__ Wy110,
    const float* __restrict__ Wy011, const float* __restrict__ Wy101,
    const float* __restrict__ Wy111,
    const float* __restrict__ Wm1, const float* __restrict__ Wm2,
    const float* __restrict__ Wm3,
    ushort* __restrict__ W0b, ushort* __restrict__ Wm1b,
    ushort* __restrict__ Wm2b, ushort* __restrict__ Wm3b,
    ushort* __restrict__ WVb)
{
    int g = blockIdx.x * 256 + threadIdx.x;
    if (g < 128 * 64) {           // W0b[o][c] : c<32 -> Wy000, else Wy110
        int o = g >> 6, c = g & 63;
        float v = (c < 32) ? Wy000[o * 32 + c] : Wy110[o * 32 + (c - 32)];
        W0b[g] = f2bf(v);
    }
    if (g < 128 * 128) {
        Wm1b[g] = f2bf(Wm1[g]);
        Wm2b[g] = f2bf(Wm2[g]);
        Wm3b[g] = f2bf(Wm3[g]);
    }
    if (g < 32 * 96) {            // WVb[d][k]: k<32 Wy011, <64 Wy101, else Wy111
        int d = g / 96, k = g % 96;
        float v = (k < 32) ? Wy011[d * 32 + k]
                : (k < 64) ? Wy101[d * 32 + (k - 32)]
                           : Wy111[d * 32 + (k - 64)];
        WVb[g] = f2bf(v);
    }
}

// ---------------- node projection kernel ----------------
__global__ __launch_bounds__(256) void node_proj_kernel(
    const float* __restrict__ x_a, const float* __restrict__ x_v,
    const float* __restrict__ W_L0, const float* __restrict__ W_L1,
    float* __restrict__ L0, float* __restrict__ L1)
{
    int t = threadIdx.x;
    int n = blockIdx.x * 8 + (t >> 5);
    int c = t & 31;
    if (n >= N_NODES) return;

    const float4* xa = (const float4*)(x_a + (size_t)n * DIM_A);
    const float4* w0 = (const float4*)(W_L0 + c * DIM_A);
    float acc = 0.f;
#pragma unroll 8
    for (int k = 0; k < DIM_A / 4; ++k) {
        float4 x = xa[k]; float4 w = w0[k];
        acc += x.x * w.x + x.y * w.y + x.z * w.z + x.w * w.w;
    }
    L0[(size_t)n * 32 + c] = acc;

    const float* xv = x_v + (size_t)n * DIM_V * 3;
    const float* w1 = W_L1 + c * DIM_V;
    float a0 = 0.f, a1 = 0.f, a2 = 0.f;
#pragma unroll 8
    for (int d = 0; d < DIM_V; ++d) {
        float w = w1[d];
        a0 += xv[d * 3 + 0] * w;
        a1 += xv[d * 3 + 1] * w;
        a2 += xv[d * 3 + 2] * w;
    }
    float* o = L1 + (size_t)n * 96 + c * 3;
    o[0] = a0; o[1] = a1; o[2] = a2;
}

// ---------------- counting sort by src ----------------
__global__ __launch_bounds__(256) void hist_kernel(const int* __restrict__ src,
                                                   int* __restrict__ deg)
{
    int i = blockIdx.x * 256 + threadIdx.x;
    if (i < N_EDGES) atomicAdd(&deg[src[i]], 1);
}

__global__ __launch_bounds__(1024) void scan_kernel(const int* __restrict__ deg,
                                                    int* __restrict__ offs,
                                                    int* __restrict__ cursor)
{
    __shared__ int buf[1024];
    __shared__ int s_carry;
    int t = threadIdx.x;
    if (t == 0) s_carry = 0;
    __syncthreads();
    for (int base = 0; base < N_NODES; base += 1024) {
        int v = (base + t < N_NODES) ? deg[base + t] : 0;
        buf[t] = v;
        __syncthreads();
        for (int off = 1; off < 1024; off <<= 1) {
            int x = (t >= off) ? buf[t - off] : 0;
            __syncthreads();
            buf[t] += x;
            __syncthreads();
        }
        int incl = buf[t];
        int carry = s_carry;
        if (base + t < N_NODES) {
            int excl = carry + incl - v;
            offs[base + t] = excl;
            cursor[base + t] = excl;
        }
        __syncthreads();
        if (t == 1023) s_carry = carry + incl;
        __syncthreads();
    }
    if (t == 0) offs[N_NODES] = s_carry;
}

__global__ __launch_bounds__(256) void scatter_kernel(const int* __restrict__ src,
                                                      int* __restrict__ cursor,
                                                      int* __restrict__ eids)
{
    int i = blockIdx.x * 256 + threadIdx.x;
    if (i < N_EDGES) {
        int p = atomicAdd(&cursor[src[i]], 1);
        eids[p] = i;
    }
}

// ---------------- MFMA edge kernel (barrier-free) ----------------
// LDS (ushort/bf16), padded row strides (2-way bank aliasing only = free):
//   sY0 [64][72]   cols 0..31 = y000, 32..63 = y110
//   sYv[i][64][104] cols 0..31 = y011_i, 32..63 = y101_i, 64..95 = y111_i
//   sACT [64][136]  activation ping (psi0 -> h1 -> h2), bf16
// Wave w owns edge rows [16w, 16w+16): phase-1 writers (t>>2 in that range)
// and phase-2 readers/writers coincide -> no __syncthreads needed anywhere.
__global__ __launch_bounds__(256, 2) void edge_mfma_kernel(
    const float* __restrict__ r_ij, const int* __restrict__ dst,
    const int* __restrict__ eids,
    const float* __restrict__ L0, const float* __restrict__ L1,
    const float* __restrict__ W_enc, const float* __restrict__ b_enc,
    const ushort* __restrict__ W0b, const ushort* __restrict__ Wm1b,
    const ushort* __restrict__ Wm2b, const ushort* __restrict__ Wm3b,
    const ushort* __restrict__ WVb,
    const float* __restrict__ bm1, const float* __restrict__ bm2,
    ushort* __restrict__ psiA, ushort* __restrict__ psiV)
{
    __shared__ __align__(16) ushort sY0[64 * 72];
    __shared__ __align__(16) ushort sYv[3][64 * 104];
    __shared__ __align__(16) ushort sACT[64 * 136];

    const int t = threadIdx.x;
    const int e0 = blockIdx.x * EB;

    // ---- phase 1: build bf16 feature matrices ----
    {
        const int e = t >> 2;          // 0..63  (wave w handles e in [16w,16w+16))
        const int p = t & 3;           // 4 threads/edge, 8 channels each
        const int ee = min(e0 + e, N_EDGES - 1);
        const int eid = eids[ee];

        float rx = r_ij[eid * 3 + 0];
        float ry = r_ij[eid * 3 + 1];
        float rz = r_ij[eid * 3 + 2];
        float r = sqrtf(rx * rx + ry * ry + rz * rz);

        float rad[8];
#pragma unroll
        for (int k = 0; k < 8; ++k) {
            float d = (r - (5.0f / 7.0f) * (float)k) * 1.6f;
            rad[k] = expf(-d * d);
        }
        float n14 = 1.4f * r;
        float tt = tanhf(n14) / fmaxf(n14, 1e-6f);
        float rsx = 1.4f * rx * tt, rsy = 1.4f * ry * tt, rsz = 1.4f * rz * tt;

        int dn = dst[eid];
        float la[8];
        {
            const float4* lap = (const float4*)(L0 + (size_t)dn * 32 + p * 8);
            float4 A = lap[0], B = lap[1];
            la[0] = A.x; la[1] = A.y; la[2] = A.z; la[3] = A.w;
            la[4] = B.x; la[5] = B.y; la[6] = B.z; la[7] = B.w;
        }
        float lv[24];
        {
            const float4* lvp = (const float4*)(L1 + (size_t)dn * 96 + p * 24);
#pragma unroll
            for (int q = 0; q < 6; ++q) {
                float4 v = lvp[q];
                lv[q * 4 + 0] = v.x; lv[q * 4 + 1] = v.y;
                lv[q * 4 + 2] = v.z; lv[q * 4 + 3] = v.w;
            }
        }

        ushort8 u000, u110, u011[3], u101[3], u111[3];
#pragma unroll
        for (int j = 0; j < 8; ++j) {
            int c = p * 8 + j;
            float re = b_enc[c];
#pragma unroll
            for (int k = 0; k < 8; ++k) re += rad[k] * W_enc[c * 8 + k];
            float lvx = lv[j * 3 + 0], lvy = lv[j * 3 + 1], lvz = lv[j * 3 + 2];
            float dotv = lvx * rsx + lvy * rsy + lvz * rsz;
            float cx = lvy * rsz - lvz * rsy;
            float cy = lvz * rsx - lvx * rsz;
            float cz = lvx * rsy - lvy * rsx;
            float y000 = la[j] * re;
            u000[j] = f2bf(y000);
            u110[j] = f2bf(re * dotv);
            u011[0][j] = f2bf(y000 * rsx);
            u011[1][j] = f2bf(y000 * rsy);
            u011[2][j] = f2bf(y000 * rsz);
            u101[0][j] = f2bf(re * lvx);
            u101[1][j] = f2bf(re * lvy);
            u101[2][j] = f2bf(re * lvz);
            u111[0][j] = f2bf(re * cx);
            u111[1][j] = f2bf(re * cy);
            u111[2][j] = f2bf(re * cz);
        }
        *(ushort8*)&sY0[e * 72 + p * 8]      = u000;
        *(ushort8*)&sY0[e * 72 + 32 + p * 8] = u110;
#pragma unroll
        for (int i = 0; i < 3; ++i) {
            *(ushort8*)&sYv[i][e * 104 + p * 8]      = u011[i];
            *(ushort8*)&sYv[i][e * 104 + 32 + p * 8] = u101[i];
            *(ushort8*)&sYv[i][e * 104 + 64 + p * 8] = u111[i];
        }
    }
    // no barrier: wave-row partitioning, same-wave DS ops are ordered

    // ---- phase 2: MFMA chain ----
    const int lane = t & 63;
    const int w = t >> 6;
    const int r0 = lane & 15;
    const int quad = lane >> 4;
    const int arow = w * 16 + r0;

    // psi0 = Y0 @ W0cat^T   (K=64), keep fp32 residual in regs, bf16 to sACT
    f32x4 p0[8];
    {
        short8 aY[2];
        aY[0] = *(const short8*)&sY0[arow * 72 + quad * 8];
        aY[1] = *(const short8*)&sY0[arow * 72 + 32 + quad * 8];
#pragma unroll
        for (int nt = 0; nt < 8; ++nt) {
            f32x4 acc = {0.f, 0.f, 0.f, 0.f};
#pragma unroll
            for (int kb = 0; kb < 2; ++kb) {
                short8 b = *(const short8*)&W0b[(nt * 16 + r0) * 64 + kb * 32 + quad * 8];
                acc = __builtin_amdgcn_mfma_f32_16x16x32_bf16(aY[kb], b, acc, 0, 0, 0);
            }
            p0[nt] = acc;
#pragma unroll
            for (int rr = 0; rr < 4; ++rr)
                sACT[(w * 16 + quad * 4 + rr) * 136 + nt * 16 + r0] = f2bf(acc[rr]);
        }
    }

    // h1, h2  (K=128, bias + leaky)
    const ushort* Wl[2] = { Wm1b, Wm2b };
    const float*  bl[2] = { bm1, bm2 };
#pragma unroll 1
    for (int layer = 0; layer < 2; ++layer) {
        short8 af[4];
#pragma unroll
        for (int kb = 0; kb < 4; ++kb)
            af[kb] = *(const short8*)&sACT[arow * 136 + kb * 32 + quad * 8];
        f32x4 hv[8];
#pragma unroll
        for (int nt = 0; nt < 8; ++nt) {
            float bv = bl[layer][nt * 16 + r0];
            f32x4 acc = {bv, bv, bv, bv};
#pragma unroll
            for (int kb = 0; kb < 4; ++kb) {
                short8 b = *(const short8*)&Wl[layer][(nt * 16 + r0) * 128 + kb * 32 + quad * 8];
                acc = __builtin_amdgcn_mfma_f32_16x16x32_bf16(af[kb], b, acc, 0, 0, 0);
            }
#pragma unroll
            for (int rr = 0; rr < 4; ++rr) acc[rr] = leaky(acc[rr]);
            hv[nt] = acc;
        }
#pragma unroll
        for (int nt = 0; nt < 8; ++nt)
#pragma unroll
            for (int rr = 0; rr < 4; ++rr)
                sACT[(w * 16 + quad * 4 + rr) * 136 + nt * 16 + r0] = f2bf(hv[nt][rr]);
    }

    // final: psi_a = psi0 + h2 @ Wm3^T  -> global bf16 (sorted edge order)
    {
        short8 af[4];
#pragma unroll
        for (int kb = 0; kb < 4; ++kb)
            af[kb] = *(const short8*)&sACT[arow * 136 + kb * 32 + quad * 8];
#pragma unroll
        for (int nt = 0; nt < 8; ++nt) {
            f32x4 acc = {0.f, 0.f, 0.f, 0.f};
#pragma unroll
            for (int kb = 0; kb < 4; ++kb) {
                short8 b = *(const short8*)&Wm3b[(nt * 16 + r0) * 128 + kb * 32 + quad * 8];
                acc = __builtin_amdgcn_mfma_f32_16x16x32_bf16(af[kb], b, acc, 0, 0, 0);
            }
#pragma unroll
            for (int rr = 0; rr < 4; ++rr) {
                int er = e0 + w * 16 + quad * 4 + rr;
                if (er < N_EDGES)
                    psiA[(size_t)er * 128 + nt * 16 + r0] = f2bf(acc[rr] + p0[nt][rr]);
            }
        }
    }

    // psi_v: for each spatial i: Yv_i @ WVcat^T  (K=96) -> global bf16 planes
#pragma unroll 1
    for (int i = 0; i < 3; ++i) {
        short8 av[3];
#pragma unroll
        for (int kb = 0; kb < 3; ++kb)
            av[kb] = *(const short8*)&sYv[i][arow * 104 + kb * 32 + quad * 8];
        ushort* plane = psiV + (size_t)i * N_EDGES * 32;
#pragma unroll
        for (int nt = 0; nt < 2; ++nt) {
            f32x4 acc = {0.f, 0.f, 0.f, 0.f};
#pragma unroll
            for (int kb = 0; kb < 3; ++kb) {
                short8 b = *(const short8*)&WVb[(nt * 16 + r0) * 96 + kb * 32 + quad * 8];
                acc = __builtin_amdgcn_mfma_f32_16x16x32_bf16(av[kb], b, acc, 0, 0, 0);
            }
#pragma unroll
            for (int rr = 0; rr < 4; ++rr) {
                int er = e0 + w * 16 + quad * 4 + rr;
                if (er < N_EDGES)
                    plane[(size_t)er * 32 + nt * 16 + r0] = f2bf(acc[rr]);
            }
        }
    }
}

// ---------------- segmented reduction (1 wave per node) ----------------
__global__ __launch_bounds__(256) void reduce_kernel(
    const int* __restrict__ offs, const ushort* __restrict__ psiA,
    const ushort* __restrict__ psiV,
    float* __restrict__ B_a, float* __restrict__ B_v)
{
    int n = blockIdx.x * 4 + (threadIdx.x >> 6);
    int lane = threadIdx.x & 63;
    if (n >= N_NODES) return;
    int p0 = offs[n], p1 = offs[n + 1];

    float a0 = 0.f, a1 = 0.f;
    for (int p = p0; p < p1; ++p) {
        unsigned int u = *(const unsigned int*)&psiA[(size_t)p * 128 + lane * 2];
        a0 += bf2f((ushort)(u & 0xffff));
        a1 += bf2f((ushort)(u >> 16));
    }
    B_a[(size_t)n * 128 + lane * 2 + 0] = 0.1f * a0;
    B_a[(size_t)n * 128 + lane * 2 + 1] = 0.1f * a1;

    if (lane < 32) {
        float v0 = 0.f, v1 = 0.f, v2 = 0.f;
        const ushort* pl0 = psiV;
        const ushort* pl1 = psiV + (size_t)N_EDGES * 32;
        const ushort* pl2 = psiV + (size_t)2 * N_EDGES * 32;
        for (int p = p0; p < p1; ++p) {
            v0 += bf2f(pl0[(size_t)p * 32 + lane]);
            v1 += bf2f(pl1[(size_t)p * 32 + lane]);
            v2 += bf2f(pl2[(size_t)p * 32 + lane]);
        }
        float* o = B_v + (size_t)n * 96 + lane * 3;
        o[0] = 0.1f * v0; o[1] = 0.1f * v1; o[2] = 0.1f * v2;
    }
}

extern "C" void kernel_launch(void* const* d_in, const int* in_sizes, int n_in,
                              void* d_out, int out_size, void* d_ws, size_t ws_size,
                              hipStream_t stream) {
    const float* x_a   = (const float*)d_in[0];
    const float* x_v   = (const float*)d_in[1];
    const float* r_ij  = (const float*)d_in[2];
    const int*   src   = (const int*)d_in[3];
    const int*   dst   = (const int*)d_in[4];
    const float* W_L0  = (const float*)d_in[5];
    const float* W_L1  = (const float*)d_in[6];
    const float* W_enc = (const float*)d_in[7];
    const float* b_enc = (const float*)d_in[8];
    const float* Wy000 = (const float*)d_in[9];
    const float* Wy110 = (const float*)d_in[10];
    const float* Wy011 = (const float*)d_in[11];
    const float* Wy101 = (const float*)d_in[12];
    const float* Wy111 = (const float*)d_in[13];
    const float* Wm1   = (const float*)d_in[14];
    const float* bm1   = (const float*)d_in[15];
    const float* Wm2   = (const float*)d_in[16];
    const float* bm2   = (const float*)d_in[17];
    const float* Wm3   = (const float*)d_in[18];

    float* out = (float*)d_out;
    float* B_a = out;
    float* B_v = out + (size_t)N_NODES * DIM_A;

    char* w = (char*)d_ws;
    float* L0     = (float*)w;  w += (size_t)N_NODES * 32 * 4;
    float* L1     = (float*)w;  w += (size_t)N_NODES * 96 * 4;
    int*   deg    = (int*)w;    w += (size_t)N_NODES * 4;
    int*   offs   = (int*)w;    w += (size_t)(N_NODES + 16) * 4;
    int*   cursor = (int*)w;    w += (size_t)N_NODES * 4;
    int*   eids   = (int*)w;    w += (size_t)N_EDGES * 4;
    ushort* W0b   = (ushort*)w; w += 128 * 64 * 2;
    ushort* Wm1b  = (ushort*)w; w += 128 * 128 * 2;
    ushort* Wm2b  = (ushort*)w; w += 128 * 128 * 2;
    ushort* Wm3b  = (ushort*)w; w += 128 * 128 * 2;
    ushort* WVb   = (ushort*)w; w += 32 * 96 * 2;
    ushort* psiA  = (ushort*)w; w += (size_t)N_EDGES * 128 * 2;
    ushort* psiV  = (ushort*)w; w += (size_t)N_EDGES * 32 * 3 * 2;

    hipMemsetAsync(deg, 0, N_NODES * sizeof(int), stream);

    convw_kernel<<<64, 256, 0, stream>>>(Wy000, Wy110, Wy011, Wy101, Wy111,
                                         Wm1, Wm2, Wm3,
                                         W0b, Wm1b, Wm2b, Wm3b, WVb);
    node_proj_kernel<<<(N_NODES + 7) / 8, 256, 0, stream>>>(x_a, x_v, W_L0, W_L1, L0, L1);
    hist_kernel<<<(N_EDGES + 255) / 256, 256, 0, stream>>>(src, deg);
    scan_kernel<<<1, 1024, 0, stream>>>(deg, offs, cursor);
    scatter_kernel<<<(N_EDGES + 255) / 256, 256, 0, stream>>>(src, cursor, eids);

    edge_mfma_kernel<<<(N_EDGES + EB - 1) / EB, 256, 0, stream>>>(
        r_ij, dst, eids, L0, L1, W_enc, b_enc,
        W0b, Wm1b, Wm2b, Wm3b, WVb, bm1, bm2, psiA, psiV);

    reduce_kernel<<<(N_NODES + 3) / 4, 256, 0, stream>>>(offs, psiA, psiV, B_a, B_v);
}

// Round 4
// 966.693 us; speedup vs baseline: 6.5717x; 1.0374x over previous
//
#include <hip/hip_runtime.h>
#include <hip/hip_bf16.h>

#define N_NODES 50000
#define N_EDGES 500000
#define DIM_A 128
#define DIM_V 32
#define CHAN 32
#define EB 64            // edges per block in edge kernel
#define SCAN_B 49        // ceil(50000/1024)

typedef __attribute__((ext_vector_type(8))) short short8;
typedef __attribute__((ext_vector_type(8))) unsigned short ushort8;
typedef __attribute__((ext_vector_type(4))) float f32x4;
typedef unsigned short ushort;

__device__ __forceinline__ ushort f2bf(float x) {
    __hip_bfloat16 h = __float2bfloat16(x);
    return *reinterpret_cast<ushort*>(&h);
}
__device__ __forceinline__ float bf2f(ushort u) {
    union { float f; unsigned int i; } v; v.i = ((unsigned int)u) << 16; return v.f;
}
__device__ __forceinline__ float leaky(float x) {
    return x >= 0.f ? x : 0.1f * x;
}

// ---------------- weight conversion ----------------
__global__ __launch_bounds__(256) void convw_kernel(
    const float* __restrict__ Wy000, const float* __restrict__ Wy110,
    const float* __restrict__ Wy011, const float* __restrict__ Wy101,
    const float* __restrict__ Wy111,
    const float* __restrict__ Wm1, const float* __restrict__ Wm2,
    const float* __restrict__ Wm3,
    ushort* __restrict__ W0b, ushort* __restrict__ Wm1b,
    ushort* __restrict__ Wm2b, ushort* __restrict__ Wm3b,
    ushort* __restrict__ W011b, ushort* __restrict__ W101b,
    ushort* __restrict__ W111b)
{
    int g = blockIdx.x * 256 + threadIdx.x;
    if (g < 128 * 64) {           // W0b[o][c]: c<32 -> Wy000, else Wy110
        int o = g >> 6, c = g & 63;
        float v = (c < 32) ? Wy000[o * 32 + c] : Wy110[o * 32 + (c - 32)];
        W0b[g] = f2bf(v);
    }
    if (g < 128 * 128) {
        Wm1b[g] = f2bf(Wm1[g]);
        Wm2b[g] = f2bf(Wm2[g]);
        Wm3b[g] = f2bf(Wm3[g]);
    }
    if (g < 32 * 32) {
        W011b[g] = f2bf(Wy011[g]);
        W101b[g] = f2bf(Wy101[g]);
        W111b[g] = f2bf(Wy111[g]);
    }
}

// ---------------- node projection: LN[n][128] = [L0(32) | L1(96, c*3+i)] ----
__global__ __launch_bounds__(256) void node_proj_kernel(
    const float* __restrict__ x_a, const float* __restrict__ x_v,
    const float* __restrict__ W_L0, const float* __restrict__ W_L1,
    float* __restrict__ LN)
{
    int t = threadIdx.x;
    int n = blockIdx.x * 8 + (t >> 5);
    int c = t & 31;
    if (n >= N_NODES) return;

    const float4* xa = (const float4*)(x_a + (size_t)n * DIM_A);
    const float4* w0 = (const float4*)(W_L0 + c * DIM_A);
    float acc = 0.f;
#pragma unroll 8
    for (int k = 0; k < DIM_A / 4; ++k) {
        float4 x = xa[k]; float4 w = w0[k];
        acc += x.x * w.x + x.y * w.y + x.z * w.z + x.w * w.w;
    }
    LN[(size_t)n * 128 + c] = acc;

    const float* xv = x_v + (size_t)n * DIM_V * 3;
    const float* w1 = W_L1 + c * DIM_V;
    float a0 = 0.f, a1 = 0.f, a2 = 0.f;
#pragma unroll 8
    for (int d = 0; d < DIM_V; ++d) {
        float w = w1[d];
        a0 += xv[d * 3 + 0] * w;
        a1 += xv[d * 3 + 1] * w;
        a2 += xv[d * 3 + 2] * w;
    }
    float* o = LN + (size_t)n * 128 + 32 + c * 3;
    o[0] = a0; o[1] = a1; o[2] = a2;
}

// ---------------- dual histogram ----------------
__global__ __launch_bounds__(256) void hist2_kernel(
    const int* __restrict__ src, const int* __restrict__ dst,
    int* __restrict__ degS, int* __restrict__ degD)
{
    int i = blockIdx.x * 256 + threadIdx.x;
    if (i < N_EDGES) {
        atomicAdd(&degS[src[i]], 1);
        atomicAdd(&degD[dst[i]], 1);
    }
}

// ---------------- 3-phase multi-block exclusive scan ----------------
__global__ __launch_bounds__(1024) void scan1_kernel(const int* __restrict__ deg,
                                                     int* __restrict__ excl,
                                                     int* __restrict__ bsum)
{
    __shared__ int buf[1024];
    int t = threadIdx.x;
    int i = blockIdx.x * 1024 + t;
    int v = (i < N_NODES) ? deg[i] : 0;
    buf[t] = v;
    __syncthreads();
    for (int off = 1; off < 1024; off <<= 1) {
        int x = (t >= off) ? buf[t - off] : 0;
        __syncthreads();
        buf[t] += x;
        __syncthreads();
    }
    if (i < N_NODES) excl[i] = buf[t] - v;
    if (t == 1023) bsum[blockIdx.x] = buf[1023];
}

__global__ void scan2_kernel(int* __restrict__ bsum)
{
    if (threadIdx.x == 0) {
        int s = 0;
        for (int k = 0; k < SCAN_B; ++k) { int x = bsum[k]; bsum[k] = s; s += x; }
    }
}

__global__ __launch_bounds__(1024) void scan3_kernel(const int* __restrict__ excl,
                                                     const int* __restrict__ bsum,
                                                     int* __restrict__ offs,
                                                     int* __restrict__ cursor)
{
    int t = threadIdx.x;
    int i = blockIdx.x * 1024 + t;
    if (i < N_NODES) {
        int o = excl[i] + bsum[blockIdx.x];
        offs[i] = o;
        cursor[i] = o;
    }
    if (i == 0) offs[N_NODES] = N_EDGES;
}

// ---------------- scatter: src slots, then dst-order packed edge records ----
__global__ __launch_bounds__(256) void scatterS_kernel(const int* __restrict__ src,
                                                       int* __restrict__ curS,
                                                       int* __restrict__ srcPos)
{
    int i = blockIdx.x * 256 + threadIdx.x;
    if (i < N_EDGES) srcPos[i] = atomicAdd(&curS[src[i]], 1);
}

__global__ __launch_bounds__(256) void scatterD_kernel(
    const int* __restrict__ dst, const float* __restrict__ r_ij,
    const int* __restrict__ srcPos, int* __restrict__ curD,
    float4* __restrict__ edgeD, int* __restrict__ sposD)
{
    int i = blockIdx.x * 256 + threadIdx.x;
    if (i < N_EDGES) {
        int d = dst[i];
        int p = atomicAdd(&curD[d], 1);
        edgeD[p] = make_float4(r_ij[i * 3 + 0], r_ij[i * 3 + 1], r_ij[i * 3 + 2],
                               __int_as_float(d));
        sposD[p] = srcPos[i];
    }
}

// ---------------- MFMA edge kernel (barrier-free, dst-order, 4 blocks/CU) ---
// LDS exactly 40960 B: sY0 9216 + sRELV 13312 + sACT 17408 + sRS 1024.
__global__ __launch_bounds__(256, 4) void edge_mfma_kernel(
    const float4* __restrict__ edgeD, const int* __restrict__ sposD,
    const float* __restrict__ LN,
    const float* __restrict__ W_enc, const float* __restrict__ b_enc,
    const ushort* __restrict__ W0b, const ushort* __restrict__ Wm1b,
    const ushort* __restrict__ Wm2b, const ushort* __restrict__ Wm3b,
    const ushort* __restrict__ W011b, const ushort* __restrict__ W101b,
    const ushort* __restrict__ W111b,
    const float* __restrict__ bm1, const float* __restrict__ bm2,
    ushort* __restrict__ psiA, ushort* __restrict__ psiV)
{
    __shared__ __align__(16) ushort sY0[64 * 72];     // [e][72]: 0..31 y000, 32..63 y110
    __shared__ __align__(16) ushort sRELV[64 * 104];  // [e][104]: i*32+c = re*lv_i
    __shared__ __align__(16) ushort sACT[64 * 136];   // [e][136] activations
    __shared__ __align__(16) float sRS[64 * 4];       // [e]: rsx,rsy,rsz,spos-bits

    const int t = threadIdx.x;
    const int e0 = blockIdx.x * EB;

    // ---- phase 1: per-edge features -> LDS (wave-row partitioned) ----
    {
        const int e = t >> 2;          // wave w owns e in [16w,16w+16)
        const int p = t & 3;           // 8 channels each
        const int qe = min(e0 + e, N_EDGES - 1);
        float4 ed = edgeD[qe];
        int spos = sposD[qe];
        float rx = ed.x, ry = ed.y, rz = ed.z;
        int dn = __float_as_int(ed.w);
        float r = sqrtf(rx * rx + ry * ry + rz * rz);

        float rad[8];
#pragma unroll
        for (int k = 0; k < 8; ++k) {
            float d = (r - (5.0f / 7.0f) * (float)k) * 1.6f;
            rad[k] = expf(-d * d);
        }
        float n14 = 1.4f * r;
        float tt = tanhf(n14) / fmaxf(n14, 1e-6f);
        float rsx = 1.4f * rx * tt, rsy = 1.4f * ry * tt, rsz = 1.4f * rz * tt;
        if (p == 0) {
            *(float4*)&sRS[e * 4] = make_float4(rsx, rsy, rsz, __int_as_float(spos));
        }

        float la[8];
        {
            const float4* lap = (const float4*)(LN + (size_t)dn * 128 + p * 8);
            float4 A = lap[0], B = lap[1];
            la[0] = A.x; la[1] = A.y; la[2] = A.z; la[3] = A.w;
            la[4] = B.x; la[5] = B.y; la[6] = B.z; la[7] = B.w;
        }
        float lv[24];
        {
            const float4* lvp = (const float4*)(LN + (size_t)dn * 128 + 32 + p * 24);
#pragma unroll
            for (int q = 0; q < 6; ++q) {
                float4 v = lvp[q];
                lv[q * 4 + 0] = v.x; lv[q * 4 + 1] = v.y;
                lv[q * 4 + 2] = v.z; lv[q * 4 + 3] = v.w;
            }
        }

        ushort8 u000, u110, url[3];
#pragma unroll
        for (int j = 0; j < 8; ++j) {
            int c = p * 8 + j;
            float re = b_enc[c];
#pragma unroll
            for (int k = 0; k < 8; ++k) re += rad[k] * W_enc[c * 8 + k];
            float lvx = lv[j * 3 + 0], lvy = lv[j * 3 + 1], lvz = lv[j * 3 + 2];
            float dotv = lvx * rsx + lvy * rsy + lvz * rsz;
            u000[j] = f2bf(la[j] * re);
            u110[j] = f2bf(re * dotv);
            url[0][j] = f2bf(re * lvx);
            url[1][j] = f2bf(re * lvy);
            url[2][j] = f2bf(re * lvz);
        }
        *(ushort8*)&sY0[e * 72 + p * 8]      = u000;
        *(ushort8*)&sY0[e * 72 + 32 + p * 8] = u110;
#pragma unroll
        for (int i = 0; i < 3; ++i)
            *(ushort8*)&sRELV[e * 104 + i * 32 + p * 8] = url[i];
    }
    // no barrier: same-wave LDS ordering via lgkmcnt

    // ---- phase 2: MFMA chain ----
    const int lane = t & 63;
    const int w = t >> 6;
    const int r0 = lane & 15;
    const int quad = lane >> 4;
    const int arow = w * 16 + r0;

    // psi0 = Y0 @ W0cat^T (K=64); fp32 residual in regs, bf16 to sACT
    f32x4 p0[8];
    {
        short8 aY[2];
        aY[0] = *(const short8*)&sY0[arow * 72 + quad * 8];
        aY[1] = *(const short8*)&sY0[arow * 72 + 32 + quad * 8];
#pragma unroll
        for (int nt = 0; nt < 8; ++nt) {
            f32x4 acc = {0.f, 0.f, 0.f, 0.f};
#pragma unroll
            for (int kb = 0; kb < 2; ++kb) {
                short8 b = *(const short8*)&W0b[(nt * 16 + r0) * 64 + kb * 32 + quad * 8];
                acc = __builtin_amdgcn_mfma_f32_16x16x32_bf16(aY[kb], b, acc, 0, 0, 0);
            }
            p0[nt] = acc;
#pragma unroll
            for (int rr = 0; rr < 4; ++rr)
                sACT[(w * 16 + quad * 4 + rr) * 136 + nt * 16 + r0] = f2bf(acc[rr]);
        }
    }

    // h1 = leaky(act @ Wm1^T + bm1)
    {
        short8 af[4];
#pragma unroll
        for (int kb = 0; kb < 4; ++kb)
            af[kb] = *(const short8*)&sACT[arow * 136 + kb * 32 + quad * 8];
        f32x4 hv[8];
#pragma unroll
        for (int nt = 0; nt < 8; ++nt) {
            float bv = bm1[nt * 16 + r0];
            f32x4 acc = {bv, bv, bv, bv};
#pragma unroll
            for (int kb = 0; kb < 4; ++kb) {
                short8 b = *(const short8*)&Wm1b[(nt * 16 + r0) * 128 + kb * 32 + quad * 8];
                acc = __builtin_amdgcn_mfma_f32_16x16x32_bf16(af[kb], b, acc, 0, 0, 0);
            }
#pragma unroll
            for (int rr = 0; rr < 4; ++rr) acc[rr] = leaky(acc[rr]);
            hv[nt] = acc;
        }
#pragma unroll
        for (int nt = 0; nt < 8; ++nt)
#pragma unroll
            for (int rr = 0; rr < 4; ++rr)
                sACT[(w * 16 + quad * 4 + rr) * 136 + nt * 16 + r0] = f2bf(hv[nt][rr]);
    }

    // h2 = leaky(act @ Wm2^T + bm2)
    {
        short8 af[4];
#pragma unroll
        for (int kb = 0; kb < 4; ++kb)
            af[kb] = *(const short8*)&sACT[arow * 136 + kb * 32 + quad * 8];
        f32x4 hv[8];
#pragma unroll
        for (int nt = 0; nt < 8; ++nt) {
            float bv = bm2[nt * 16 + r0];
            f32x4 acc = {bv, bv, bv, bv};
#pragma unroll
            for (int kb = 0; kb < 4; ++kb) {
                short8 b = *(const short8*)&Wm2b[(nt * 16 + r0) * 128 + kb * 32 + quad * 8];
                acc = __builtin_amdgcn_mfma_f32_16x16x32_bf16(af[kb], b, acc, 0, 0, 0);
            }
#pragma unroll
            for (int rr = 0; rr < 4; ++rr) acc[rr] = leaky(acc[rr]);
            hv[nt] = acc;
        }
#pragma unroll
        for (int nt = 0; nt < 8; ++nt)
#pragma unroll
            for (int rr = 0; rr < 4; ++rr)
                sACT[(w * 16 + quad * 4 + rr) * 136 + nt * 16 + r0] = f2bf(hv[nt][rr]);
    }

    // psi_a = psi0 + h2 @ Wm3^T -> scattered row store to src-sorted slot
    {
        short8 af[4];
#pragma unroll
        for (int kb = 0; kb < 4; ++kb)
            af[kb] = *(const short8*)&sACT[arow * 136 + kb * 32 + quad * 8];
        f32x4 fv[8];
#pragma unroll
        for (int nt = 0; nt < 8; ++nt) {
            f32x4 acc = {0.f, 0.f, 0.f, 0.f};
#pragma unroll
            for (int kb = 0; kb < 4; ++kb) {
                short8 b = *(const short8*)&Wm3b[(nt * 16 + r0) * 128 + kb * 32 + quad * 8];
                acc = __builtin_amdgcn_mfma_f32_16x16x32_bf16(af[kb], b, acc, 0, 0, 0);
            }
#pragma unroll
            for (int rr = 0; rr < 4; ++rr) acc[rr] += p0[nt][rr];
            fv[nt] = acc;
        }
#pragma unroll
        for (int rr = 0; rr < 4; ++rr) {
            int el = w * 16 + quad * 4 + rr;
            int spos = __float_as_int(sRS[el * 4 + 3]);
            ushort* row = psiA + (size_t)spos * 128;
#pragma unroll
            for (int nt = 0; nt < 8; ++nt)
                row[nt * 16 + r0] = f2bf(fv[nt][rr]);
        }
    }

    // psi_v via linearity: psiV[d] = s[d]*rs + T[d] + U[d] x rs
    {
        short8 aY0 = *(const short8*)&sY0[arow * 72 + quad * 8];
        short8 aRL[3];
#pragma unroll
        for (int i = 0; i < 3; ++i)
            aRL[i] = *(const short8*)&sRELV[arow * 104 + i * 32 + quad * 8];

#pragma unroll
        for (int nt = 0; nt < 2; ++nt) {
            short8 b011 = *(const short8*)&W011b[(nt * 16 + r0) * 32 + quad * 8];
            f32x4 sA = __builtin_amdgcn_mfma_f32_16x16x32_bf16(
                aY0, b011, (f32x4){0.f, 0.f, 0.f, 0.f}, 0, 0, 0);
            f32x4 U[3], T[3];
#pragma unroll
            for (int i = 0; i < 3; ++i) {
                short8 b111 = *(const short8*)&W111b[(nt * 16 + r0) * 32 + quad * 8];
                short8 b101 = *(const short8*)&W101b[(nt * 16 + r0) * 32 + quad * 8];
                U[i] = __builtin_amdgcn_mfma_f32_16x16x32_bf16(
                    aRL[i], b111, (f32x4){0.f, 0.f, 0.f, 0.f}, 0, 0, 0);
                T[i] = __builtin_amdgcn_mfma_f32_16x16x32_bf16(
                    aRL[i], b101, (f32x4){0.f, 0.f, 0.f, 0.f}, 0, 0, 0);
            }
            int d = nt * 16 + r0;
#pragma unroll
            for (int rr = 0; rr < 4; ++rr) {
                int el = w * 16 + quad * 4 + rr;
                float4 rsv = *(const float4*)&sRS[el * 4];
                int spos = __float_as_int(rsv.w);
                float s = sA[rr];
                float ux = U[0][rr], uy = U[1][rr], uz = U[2][rr];
                float ox = s * rsv.x + T[0][rr] + uy * rsv.z - uz * rsv.y;
                float oy = s * rsv.y + T[1][rr] + uz * rsv.x - ux * rsv.z;
                float oz = s * rsv.z + T[2][rr] + ux * rsv.y - uy * rsv.x;
                ushort* row = psiV + (size_t)spos * 96;
                row[0 * 32 + d] = f2bf(ox);
                row[1 * 32 + d] = f2bf(oy);
                row[2 * 32 + d] = f2bf(oz);
            }
        }
    }
}

// ---------------- segmented reduction (1 wave per node, src-sorted) ---------
__global__ __launch_bounds__(256) void reduce_kernel(
    const int* __restrict__ offsS, const ushort* __restrict__ psiA,
    const ushort* __restrict__ psiV,
    float* __restrict__ B_a, float* __restrict__ B_v)
{
    int n = blockIdx.x * 4 + (threadIdx.x >> 6);
    int lane = threadIdx.x & 63;
    if (n >= N_NODES) return;
    int p0 = offsS[n], p1 = offsS[n + 1];

    float a0 = 0.f, a1 = 0.f;
    for (int p = p0; p < p1; ++p) {
        unsigned int u = *(const unsigned int*)&psiA[(size_t)p * 128 + lane * 2];
        a0 += bf2f((ushort)(u & 0xffff));
        a1 += bf2f((ushort)(u >> 16));
    }
    B_a[(size_t)n * 128 + lane * 2 + 0] = 0.1f * a0;
    B_a[(size_t)n * 128 + lane * 2 + 1] = 0.1f * a1;

    if (lane < 48) {
        float v0 = 0.f, v1 = 0.f;
        for (int p = p0; p < p1; ++p) {
            unsigned int u = *(const unsigned int*)&psiV[(size_t)p * 96 + lane * 2];
            v0 += bf2f((ushort)(u & 0xffff));
            v1 += bf2f((ushort)(u >> 16));
        }
        int j0 = lane * 2, j1 = lane * 2 + 1;  // stored col = i*32+d; B_v idx = d*3+i
        B_v[(size_t)n * 96 + (j0 & 31) * 3 + (j0 >> 5)] = 0.1f * v0;
        B_v[(size_t)n * 96 + (j1 & 31) * 3 + (j1 >> 5)] = 0.1f * v1;
    }
}

extern "C" void kernel_launch(void* const* d_in, const int* in_sizes, int n_in,
                              void* d_out, int out_size, void* d_ws, size_t ws_size,
                              hipStream_t stream) {
    const float* x_a   = (const float*)d_in[0];
    const float* x_v   = (const float*)d_in[1];
    const float* r_ij  = (const float*)d_in[2];
    const int*   src   = (const int*)d_in[3];
    const int*   dst   = (const int*)d_in[4];
    const float* W_L0  = (const float*)d_in[5];
    const float* W_L1  = (const float*)d_in[6];
    const float* W_enc = (const float*)d_in[7];
    const float* b_enc = (const float*)d_in[8];
    const float* Wy000 = (const float*)d_in[9];
    const float* Wy110 = (const float*)d_in[10];
    const float* Wy011 = (const float*)d_in[11];
    const float* Wy101 = (const float*)d_in[12];
    const float* Wy111 = (const float*)d_in[13];
    const float* Wm1   = (const float*)d_in[14];
    const float* bm1   = (const float*)d_in[15];
    const float* Wm2   = (const float*)d_in[16];
    const float* bm2   = (const float*)d_in[17];
    const float* Wm3   = (const float*)d_in[18];

    float* out = (float*)d_out;
    float* B_a = out;
    float* B_v = out + (size_t)N_NODES * DIM_A;

    char* w = (char*)d_ws;
    float* LN     = (float*)w;  w += (size_t)N_NODES * 128 * 4;   // 25.6 MB
    int*   degS   = (int*)w;    w += (size_t)N_NODES * 4;
    int*   degD   = (int*)w;    w += (size_t)N_NODES * 4;
    int*   offsS  = (int*)w;    w += (size_t)(N_NODES + 16) * 4;
    int*   curS   = (int*)w;    w += (size_t)N_NODES * 4;
    int*   offsD  = (int*)w;    w += (size_t)(N_NODES + 16) * 4;
    int*   curD   = (int*)w;    w += (size_t)N_NODES * 4;
    int*   excl   = (int*)w;    w += (size_t)N_NODES * 4;
    int*   bsum   = (int*)w;    w += 64 * 4;
    int*   sposD  = (int*)w;    w += (size_t)N_EDGES * 4;
    float4* edgeD = (float4*)w; w += (size_t)N_EDGES * 16;
    ushort* W0b   = (ushort*)w; w += 128 * 64 * 2;
    ushort* Wm1b  = (ushort*)w; w += 128 * 128 * 2;
    ushort* Wm2b  = (ushort*)w; w += 128 * 128 * 2;
    ushort* Wm3b  = (ushort*)w; w += 128 * 128 * 2;
    ushort* W011b = (ushort*)w; w += 32 * 32 * 2;
    ushort* W101b = (ushort*)w; w += 32 * 32 * 2;
    ushort* W111b = (ushort*)w; w += 32 * 32 * 2;
    ushort* psiA  = (ushort*)w; w += (size_t)N_EDGES * 128 * 2;   // 128 MB
    ushort* psiV  = (ushort*)w; w += (size_t)N_EDGES * 96 * 2;    // 96 MB
    int*   srcPos = (int*)psiA;  // alias: consumed before psiA is written

    hipMemsetAsync(degS, 0, 2 * N_NODES * sizeof(int), stream);  // degS+degD adjacent

    convw_kernel<<<64, 256, 0, stream>>>(Wy000, Wy110, Wy011, Wy101, Wy111,
                                         Wm1, Wm2, Wm3,
                                         W0b, Wm1b, Wm2b, Wm3b, W011b, W101b, W111b);
    node_proj_kernel<<<(N_NODES + 7) / 8, 256, 0, stream>>>(x_a, x_v, W_L0, W_L1, LN);

    hist2_kernel<<<(N_EDGES + 255) / 256, 256, 0, stream>>>(src, dst, degS, degD);

    scan1_kernel<<<SCAN_B, 1024, 0, stream>>>(degS, excl, bsum);
    scan2_kernel<<<1, 64, 0, stream>>>(bsum);
    scan3_kernel<<<SCAN_B, 1024, 0, stream>>>(excl, bsum, offsS, curS);

    scan1_kernel<<<SCAN_B, 1024, 0, stream>>>(degD, excl, bsum);
    scan2_kernel<<<1, 64, 0, stream>>>(bsum);
    scan3_kernel<<<SCAN_B, 1024, 0, stream>>>(excl, bsum, offsD, curD);

    scatterS_kernel<<<(N_EDGES + 255) / 256, 256, 0, stream>>>(src, curS, srcPos);
    scatterD_kernel<<<(N_EDGES + 255) / 256, 256, 0, stream>>>(dst, r_ij, srcPos, curD,
                                                               edgeD, sposD);

    edge_mfma_kernel<<<(N_EDGES + EB - 1) / EB, 256, 0, stream>>>(
        edgeD, sposD, LN, W_enc, b_enc,
        W0b, Wm1b, Wm2b, Wm3b, W011b, W101b, W111b,
        bm1, bm2, psiA, psiV);

    reduce_kernel<<<(N_NODES + 3) / 4, 256, 0, stream>>>(offsS, psiA, psiV, B_a, B_v);
}